// Round 12
// baseline (87.580 us; speedup 1.0000x reference)
//
#include <hip/hip_runtime.h>
#include <stdint.h>

#define IN_F 2048
#define OUT_F 2048
#define N_ROWS 8192

// ---- GEMM geometry: 256x256 tile, BK=32, 8 waves (2Mx4N), 4-deep LDS.
// A: reg-staged from fp32 (hw bf16 cvt + ds_write). B: DMA from pre-tiled image.
#define BM 256
#define BN 256
#define BK 32
#define NT (IN_F / BK)             // 64 K-steps
#define TM_TILES (N_ROWS / BM)     // 32
#define TN_TILES (OUT_F / BN)      // 8
#define NWG (TM_TILES * TN_TILES)  // 256 == #CUs
#define TILE_SHORTS (BM * BK)      // 8192 shorts = 16 KiB per (tile,kstep)
#define BUF_SHORTS (2 * TILE_SHORTS)

typedef __bf16 bf16x8 __attribute__((ext_vector_type(8)));
typedef float f32x4 __attribute__((ext_vector_type(4)));
typedef unsigned short ushortx8 __attribute__((ext_vector_type(8)));

__device__ __forceinline__ unsigned short f2bf(float f) {
  unsigned u = __builtin_bit_cast(unsigned, f);
  u += 0x7FFFu + ((u >> 16) & 1u);
  return (unsigned short)(u >> 16);
}

__device__ __forceinline__ void async16(void* lds, const void* g) {
  __builtin_amdgcn_global_load_lds(
      (const __attribute__((address_space(1))) void*)(uintptr_t)g,
      (__attribute__((address_space(3))) void*)(uint32_t)(uintptr_t)lds,
      16, 0, 0);
}

__device__ __forceinline__ bf16x8 ld8(const unsigned short* p) {
  return __builtin_bit_cast(bf16x8, *reinterpret_cast<const ushortx8*>(p));
}

// 8 f32 -> 8 bf16 (hardware RNE casts; compiler emits cvt_pk pairs)
__device__ __forceinline__ ushortx8 cvt8(float4 a, float4 b) {
  bf16x8 v;
  v[0] = (__bf16)a.x; v[1] = (__bf16)a.y; v[2] = (__bf16)a.z; v[3] = (__bf16)a.w;
  v[4] = (__bf16)b.x; v[5] = (__bf16)b.y; v[6] = (__bf16)b.z; v[7] = (__bf16)b.w;
  return __builtin_bit_cast(ushortx8, v);
}

// ---- prep: B-image only (pre-tiled, pre-swizzled Ht staging image).
// Chunk t in [0,1024) of tile (Ct*64+T): row r=t>>2, slot s=t&3 holds
// k-group ga = s ^ ((r>>1)&3).
// BtT[tile*8192 + t*8 + e] = Ht[Ct*256 + r][T*32 + ga*8 + e],
//   Ht[b][a] = s(q,c) * W[u][(q^c)*512 + v]  (q=a&3,u=a>>2,c=b&3,v=b>>2)
__global__ __launch_bounds__(256) void k_prepB(const float* __restrict__ W,
                                               unsigned short* __restrict__ BtT) {
  const int bb = blockIdx.x;                     // 0..2047
  const int tile = bb >> 2;                      // Ct*64 + T, 0..511
  const int t = ((bb & 3) << 8) + threadIdx.x;
  const int r = t >> 2;
  const int ga = (t & 3) ^ ((r >> 1) & 3);
  const int Ct = tile >> 6, T = tile & 63;
  const int b = Ct * 256 + r;
  const int c = b & 3, v = b >> 2;
  const int a0 = T * 32 + ga * 8;
  ushortx8 o;
#pragma unroll
  for (int e = 0; e < 8; ++e) {
    const int a = a0 + e;
    const int q = a & 3, u = a >> 2;
    float w = W[(size_t)u * OUT_F + ((q ^ c) << 9) + v];
    if ((0x284E >> ((q << 2) | c)) & 1) w = -w;
    o[e] = f2bf(w);
  }
  *reinterpret_cast<ushortx8*>(BtT + (size_t)tile * 8192 + t * 8) = o;
}

// ---- main GEMM: C = A(fp32->bf16) @ Ht^T + bias ----
__global__ __launch_bounds__(512, 2) void k_gemm(const float* __restrict__ A,
                                                 const unsigned short* __restrict__ BtT,
                                                 const float* __restrict__ bias,
                                                 float* __restrict__ C) {
  __shared__ __align__(16) unsigned short lds[4 * BUF_SHORTS];  // 128 KiB

  const int tid = threadIdx.x;
  const int lane = tid & 63;
  const int w = tid >> 6;   // wave 0..7
  const int wm = w >> 2;    // 0..1 -> rows wm*128..+128
  const int wn = w & 3;     // 0..3 -> cols wn*64..+64
  const int fr = lane & 15;
  const int g = lane >> 4;  // k-group 0..3 (8 bf16 each)

  // XCD-bijective swizzle: 256 wgs; within an XCD consecutive = same tm row
  const int wg = blockIdx.x;
  const int swz = (wg & 7) * (NWG >> 3) + (wg >> 3);
  const int tm = swz >> 3;
  const int tn = swz & 7;
  const int row0 = tm * BM, col0 = tn * BN;

  // ---- B staging: pre-tiled image, linear DMA (2 x 1KB per wave per step)
  const unsigned short* baseB = BtT + (size_t)tn * 64 * 8192;
  const int tOff0 = (w * 128 + lane) * 8;        // shorts
  const int tOff1 = (w * 128 + 64 + lane) * 8;

#define BSTG(T)                                                        \
  do {                                                                 \
    unsigned short* d_ = &lds[((T) & 3) * BUF_SHORTS] + TILE_SHORTS;   \
    const unsigned short* sb_ = baseB + (size_t)(T) * 8192;            \
    async16(d_ + tOff0, sb_ + tOff0);                                  \
    async16(d_ + tOff1, sb_ + tOff1);                                  \
  } while (0)

  // ---- A staging: thread owns chunks c0=tid, c1=tid+512 of the A image.
  // chunk c: r=c>>2, slot s=c&3 holds k-group ga = s^((r>>1)&3).
  // c1's r = 128 + (tid>>2): same ga (128 = 0 mod 4 after >>1&3 with +64 even).
  const int ga0 = (tid & 3) ^ ((tid >> 3) & 3);
  const float* srcA0 = A + (size_t)(row0 + (tid >> 2)) * IN_F + ga0 * 8;
  const float* srcA1 = srcA0 + (size_t)128 * IN_F;

#define ALOAD(T, S_)                                                   \
  do {                                                                 \
    const float* s0_ = srcA0 + (T) * 32;                               \
    const float* s1_ = srcA1 + (T) * 32;                               \
    S_[0] = *reinterpret_cast<const float4*>(s0_);                     \
    S_[1] = *reinterpret_cast<const float4*>(s0_ + 4);                 \
    S_[2] = *reinterpret_cast<const float4*>(s1_);                     \
    S_[3] = *reinterpret_cast<const float4*>(s1_ + 4);                 \
  } while (0)

#define AWRITE(T, S_)                                                         \
  do {                                                                        \
    unsigned short* d_ = &lds[((T) & 3) * BUF_SHORTS];                        \
    *reinterpret_cast<ushortx8*>(d_ + tid * 8) = cvt8(S_[0], S_[1]);          \
    *reinterpret_cast<ushortx8*>(d_ + (tid + 512) * 8) = cvt8(S_[2], S_[3]);  \
  } while (0)

  // ---- fragment read offsets (shorts), read swizzle matches image layout
  int offA[8], offB[4];
#pragma unroll
  for (int m = 0; m < 8; ++m) {
    const int r = wm * 128 + m * 16 + fr;
    offA[m] = r * BK + ((g ^ ((r >> 1) & 3)) << 3);
  }
#pragma unroll
  for (int n = 0; n < 4; ++n) {
    const int r = wn * 64 + n * 16 + fr;
    offB[n] = TILE_SHORTS + r * BK + ((g ^ ((r >> 1) & 3)) << 3);
  }

  f32x4 acc[8][4] = {};
  float4 aE[4], aO[4];  // A reg ping-pong (static indexing only)

#define MFMA_(a_, b_, c_) __builtin_amdgcn_mfma_f32_16x16x32_bf16(a_, b_, c_, 0, 0, 0)
#define FENCE_ __builtin_amdgcn_sched_barrier(0)
#define BAR_ __builtin_amdgcn_s_barrier()
#define LGKM0_ asm volatile("s_waitcnt lgkmcnt(0)" ::: "memory")
#define VM2_ asm volatile("s_waitcnt vmcnt(2)" ::: "memory")
#define VM0_ asm volatile("s_waitcnt vmcnt(0)" ::: "memory")

  // Step T: barrier -> reads(T) -> issue A-loads(T+4) -> cvt+ds_write A(T+3)
  // (compiler's counted vmcnt here retires A(T+3) and, via in-order queue,
  // B(T+1); it always precedes barrier(T+1) -> cross-wave DMA safety)
  // -> DMA B(T+3) -> MFMA.
#define STEP(T, LD_, CV_, DOALOAD, DOSTAGE)                                   \
  do {                                                                        \
    BAR_;                                                                     \
    FENCE_;                                                                   \
    const unsigned short* b_ = &lds[((T) & 3) * BUF_SHORTS];                  \
    bf16x8 bg[4], af[8];                                                      \
    _Pragma("unroll") for (int n = 0; n < 4; ++n) bg[n] = ld8(b_ + offB[n]);  \
    _Pragma("unroll") for (int m = 0; m < 8; ++m) af[m] = ld8(b_ + offA[m]);  \
    FENCE_;                                                                   \
    if (DOALOAD) ALOAD((T) + 4, LD_);                                         \
    FENCE_;                                                                   \
    if (DOSTAGE) {                                                            \
      AWRITE((T) + 3, CV_);                                                   \
      BSTG((T) + 3);                                                          \
    }                                                                         \
    FENCE_;                                                                   \
    __builtin_amdgcn_s_setprio(1);                                            \
    _Pragma("unroll") for (int m = 0; m < 8; ++m)                             \
      _Pragma("unroll") for (int n = 0; n < 4; ++n)                           \
        acc[m][n] = MFMA_(af[m], bg[n], acc[m][n]);                           \
    __builtin_amdgcn_s_setprio(0);                                            \
    FENCE_;                                                                   \
  } while (0)

  // ---- prologue: B(0..2) via DMA; A(0..2) serial reg->LDS; A(3) in regs ----
  BSTG(0);
  BSTG(1);
  BSTG(2);
  ALOAD(0, aE); AWRITE(0, aE);  // compiler inserts the vmcnt for aE use
  ALOAD(1, aE); AWRITE(1, aE);
  ALOAD(2, aE); AWRITE(2, aE);
  ALOAD(3, aO);
  LGKM0_;  // A(0..2) ds_writes visible before first barrier
  FENCE_;

  // steady: steps 0..59 (loads A(4..63), stages tiles 3..62)
#pragma unroll 1
  for (int t = 0; t < NT - 4; t += 2) {
    STEP(t, aE, aO, true, true);      // consumes aO (tile t+3), loads aE (t+4)
    STEP(t + 1, aO, aE, true, true);  // consumes aE, loads aO
  }
  // step 60: stage tile 63 (consumes aO loaded at step 59), no more A loads
  STEP(NT - 4, aE, aO, false, true);
  // step 61: plain; own-wave VM2 before barrier(62) retires own B(62)
  {
    BAR_; FENCE_;
    const unsigned short* b_ = &lds[((NT - 3) & 3) * BUF_SHORTS];
    bf16x8 bg[4], af[8];
#pragma unroll
    for (int n = 0; n < 4; ++n) bg[n] = ld8(b_ + offB[n]);
#pragma unroll
    for (int m = 0; m < 8; ++m) af[m] = ld8(b_ + offA[m]);
    FENCE_;
    __builtin_amdgcn_s_setprio(1);
#pragma unroll
    for (int m = 0; m < 8; ++m)
#pragma unroll
      for (int n = 0; n < 4; ++n) acc[m][n] = MFMA_(af[m], bg[n], acc[m][n]);
    __builtin_amdgcn_s_setprio(0);
    FENCE_; VM2_;
  }
  // step 62
  {
    BAR_; FENCE_;
    const unsigned short* b_ = &lds[((NT - 2) & 3) * BUF_SHORTS];
    bf16x8 bg[4], af[8];
#pragma unroll
    for (int n = 0; n < 4; ++n) bg[n] = ld8(b_ + offB[n]);
#pragma unroll
    for (int m = 0; m < 8; ++m) af[m] = ld8(b_ + offA[m]);
    FENCE_;
    __builtin_amdgcn_s_setprio(1);
#pragma unroll
    for (int m = 0; m < 8; ++m)
#pragma unroll
      for (int n = 0; n < 4; ++n) acc[m][n] = MFMA_(af[m], bg[n], acc[m][n]);
    __builtin_amdgcn_s_setprio(0);
    FENCE_; VM0_;
  }
  // step 63
  {
    BAR_; FENCE_;
    const unsigned short* b_ = &lds[((NT - 1) & 3) * BUF_SHORTS];
    bf16x8 bg[4], af[8];
#pragma unroll
    for (int n = 0; n < 4; ++n) bg[n] = ld8(b_ + offB[n]);
#pragma unroll
    for (int m = 0; m < 8; ++m) af[m] = ld8(b_ + offA[m]);
    FENCE_;
    __builtin_amdgcn_s_setprio(1);
#pragma unroll
    for (int m = 0; m < 8; ++m)
#pragma unroll
      for (int n = 0; n < 4; ++n) acc[m][n] = MFMA_(af[m], bg[n], acc[m][n]);
    __builtin_amdgcn_s_setprio(0);
  }

#undef STEP
#undef BSTG
#undef ALOAD
#undef AWRITE

  // ---- epilogue: C/D layout col=lane&15, row=(lane>>4)*4+reg ----
  const int g4 = g << 2;
  float bv[4];
#pragma unroll
  for (int n = 0; n < 4; ++n) bv[n] = bias[col0 + wn * 64 + n * 16 + fr];
#pragma unroll
  for (int m = 0; m < 8; ++m) {
#pragma unroll
    for (int e = 0; e < 4; ++e) {
      const int row = row0 + wm * 128 + m * 16 + g4 + e;
      float* cp = C + (size_t)row * OUT_F + col0 + wn * 64 + fr;
#pragma unroll
      for (int n = 0; n < 4; ++n) cp[n * 16] = acc[m][n][e] + bv[n];
    }
  }
}

// ---- fallback if workspace too small: naive fp32 ----
__global__ __launch_bounds__(256) void k_naive(const float* __restrict__ A,
                                               const float* __restrict__ W,
                                               const float* __restrict__ bias,
                                               float* __restrict__ C) {
  const int idx = blockIdx.x * 256 + threadIdx.x;
  const int m = idx >> 11;
  const int b = idx & (OUT_F - 1);
  const int c = b & 3, v = b >> 2;
  float acc = 0.f;
  const float* arow = A + (size_t)m * IN_F;
  for (int a = 0; a < IN_F; ++a) {
    const int q = a & 3, u = a >> 2;
    float h = W[(size_t)u * OUT_F + ((q ^ c) << 9) + v];
    if ((0x284E >> ((q << 2) | c)) & 1) h = -h;
    acc += arow[a] * h;
  }
  C[idx] = acc + bias[b];
}

extern "C" void kernel_launch(void* const* d_in, const int* in_sizes, int n_in,
                              void* d_out, int out_size, void* d_ws, size_t ws_size,
                              hipStream_t stream) {
  (void)in_sizes; (void)n_in; (void)out_size;
  const float* inp  = (const float*)d_in[0];
  const float* w    = (const float*)d_in[1];
  const float* bias = (const float*)d_in[2];
  float* out = (float*)d_out;

  const size_t needB = (size_t)IN_F * OUT_F * sizeof(unsigned short);  // 8 MiB
  if (ws_size < needB) {
    k_naive<<<(N_ROWS * OUT_F) / 256, 256, 0, stream>>>(inp, w, bias, out);
    return;
  }

  unsigned short* BtT = (unsigned short*)d_ws;

  k_prepB<<<2048, 256, 0, stream>>>(w, BtT);
  k_gemm<<<NWG, 512, 0, stream>>>(inp, BtT, bias, out);
}